// Round 2
// baseline (243.993 us; speedup 1.0000x reference)
//
#include <hip/hip_runtime.h>

// FFB encoder fused kernel, MI355X (gfx950). Round 13.
//  R12 post-mortem: operand-swap + 32x32 head halved bank conflicts (5.57M ->
//  2.95M) and cut LDS ops/VALU as predicted, but dur was FLAT at 160 us ->
//  LDS instr count was not the critical path. All pipes <45% busy, Occupancy
//  28% (3 blocks/CU via launch_bounds(256,3)): the kernel is stall-bound.
//  R13 experiment: OCCUPANCY 3 -> 4 blocks/CU.
//   - LDS fits exactly: 40960 B x 4 = 160 KiB.
//   - (256,4) caps unified VGPR+AGPR at 128/wave. R10 spilled at ~144; R12's
//     GEMM1 phase is ~135 (C1 64 + ring-of-4 32 + gb 8 + cout 16 + misc).
//     Cut B-ring to depth-2/distance-1 (saves 16 regs -> ~119 peak):
//     weights are L2-resident (0.86 MB), L2 hit ~200 cyc < 512 cyc kb-step
//     wall at 4 waves/SIMD, so distance-1 covers with margin.
//   - Spill tripwire: WRITE_SIZE must stay ~32.8 MB (R10 spill showed 258 MB).
//  Kept from R12: GEMM1/grid operand swap (packed b64 epilogue stores),
//  32x32x16 head GEMM (wave = quadrant, x-frags reuse a1off bases),
//  K5-prescaled biases, stride-264 LDS, 2 barriers/layer, hi-only grid branch.

#define TM 64
#define XSTRIDE 264
#define GSTRIDE 48
#define K5 0.79577471545947667f         // 5/(2*pi)

typedef __attribute__((ext_vector_type(8))) _Float16 v8h;
typedef __attribute__((ext_vector_type(4))) _Float16 v4h;
typedef __attribute__((ext_vector_type(4))) float v4f;
typedef __attribute__((ext_vector_type(16))) float v16f;

#define MFMA32H(a, b, c) __builtin_amdgcn_mfma_f32_32x32x16_f16(a, b, c, 0, 0, 0)

__device__ __forceinline__ float sin_rev(float u) {
#if __has_builtin(__builtin_amdgcn_fractf)
    return __builtin_amdgcn_sinf(__builtin_amdgcn_fractf(u));
#else
    return __builtin_amdgcn_sinf(u - floorf(u));
#endif
}

__device__ __forceinline__ short f16s(float x) {      // RNE f32->f16
    _Float16 hh = (_Float16)x;
    return __builtin_bit_cast(short, hh);
}

// ---------------- weight packing ----------------
// wh   f16: [l][kb16][nt8][lane64][8]  (327680 shorts), scaled by K5
// whh  f16: [l][kb16][nt2][lane64][8]  (81920 shorts),  scaled by K5  (32-col tiles)
// gf   f16: [l][nt8][lane64][8]        (20480 shorts),  ffnA*2^(l-1)
// bhs  f32: [l][256]  = bh*K5          (1280 floats)
// bhhs f32: [l][64]   = bhh*K5         (320 floats)
__global__ __launch_bounds__(256) void ffb_pack(
    const float* __restrict__ Wh, const float* __restrict__ Whh,
    const float* __restrict__ ffnA,
    const float* __restrict__ bh, const float* __restrict__ bhh,
    short* __restrict__ wh, short* __restrict__ whh, short* __restrict__ gf,
    float* __restrict__ bhs, float* __restrict__ bhhs)
{
    int t = blockIdx.x * 256 + threadIdx.x;
    if (t < 40960) {                       // (l, kb, nt, lane)
        int lane = t & 63, nt = (t >> 6) & 7, kb = (t >> 9) & 15, l = t >> 13;
        int n = nt * 32 + (lane & 31);
        int k0 = kb * 16 + (lane >> 5) * 8;
        short hs[8];
        #pragma unroll
        for (int jj = 0; jj < 8; jj++)
            hs[jj] = f16s(Wh[(l * 256 + k0 + jj) * 256 + n] * K5);
        *(v8h*)(wh + t * 8) = *(v8h*)hs;
    } else if (t < 51200) {
        int t2 = t - 40960;                // (l, kb16, nt2, lane)
        int lane = t2 & 63, nt = (t2 >> 6) & 1, kb = (t2 >> 7) & 15, l = t2 >> 11;
        int n = nt * 32 + (lane & 31);
        int k0 = kb * 16 + (lane >> 5) * 8;
        short hs[8];
        #pragma unroll
        for (int jj = 0; jj < 8; jj++)
            hs[jj] = f16s(Whh[(l * 256 + k0 + jj) * 64 + n] * K5);
        *(v8h*)(whh + t2 * 8) = *(v8h*)hs;
    } else if (t < 53760) {
        int t3 = t - 51200;                // (l, nt, lane)
        int lane = t3 & 63, nt = (t3 >> 6) & 7, l = t3 >> 9;
        int n = nt * 32 + (lane & 31);
        const float sc = 0.5f * (float)(1 << l);       // 2^(l-1), exact
        short hs[8];
        #pragma unroll
        for (int jj = 0; jj < 8; jj++)
            hs[jj] = f16s(ffnA[(l * 8 + jj) * 256 + n] * sc);
        *(v8h*)(gf + t3 * 8) = *(v8h*)hs;
    } else if (t < 55040) {
        int t4 = t - 53760;
        bhs[t4] = bh[t4] * K5;
    } else if (t < 55360) {
        int t5 = t - 55040;
        bhhs[t5] = bhh[t5] * K5;
    }
}

// ---------------- main fused kernel ----------------
__global__ __launch_bounds__(256, 4) void ffb_main(
    const float* __restrict__ pos, const float* __restrict__ gfeat,
    const float* __restrict__ W0, const float* __restrict__ b0,
    const float* __restrict__ bhs, const float* __restrict__ bhhs,
    const short* __restrict__ wh, const short* __restrict__ whh,
    const short* __restrict__ gf,
    float* __restrict__ out)
{
    __shared__ __align__(16) short s_x[TM * XSTRIDE];   // f16  (33792 B)
    __shared__ __align__(16) short s_g[TM * GSTRIDE];   // f16  (6144 B)
    __shared__ float s_pos[TM * 3];                     //      (768 B)

    const int tid = threadIdx.x;
    const int row0 = blockIdx.x * TM;
    const int lane = tid & 63;
    const int w = tid >> 6;
    const int m32 = lane & 31;
    const int h = lane >> 5;
    const int mq = w >> 1;                 // head-GEMM quadrant row-tile
    const int tq = w & 1;                  // head-GEMM quadrant col-tile

    if (tid < TM * 3) s_pos[tid] = pos[row0 * 3 + tid];
    for (int k2 = tid; k2 < TM * 40; k2 += 256) {
        int r = k2 / 40, f = k2 % 40;
        s_g[r * GSTRIDE + f] = f16s(gfeat[row0 * 40 + k2]);
    }
    __syncthreads();

    // layer 0: x = sin(5*(pos@W0 + b0))
    {
        const int c = tid;
        const float w00 = W0[c], w01 = W0[256 + c], w02 = W0[512 + c], bc = b0[c];
        #pragma unroll 4
        for (int r = 0; r < TM; r++) {
            float d = s_pos[r * 3 + 0] * w00 + s_pos[r * 3 + 1] * w01
                    + s_pos[r * 3 + 2] * w02 + bc;
            s_x[r * XSTRIDE + c] = f16s(sin_rev(d * K5));
        }
    }
    __syncthreads();

    float cout[16];
    #pragma unroll
    for (int r = 0; r < 16; r++) cout[r] = 0.f;

    const int a1off0 = m32 * XSTRIDE + h * 8;            // x-row tile 0, + kb*16
    const int a1off1 = (32 + m32) * XSTRIDE + h * 8;     // x-row tile 1

    for (int l = 0; l < 5; l++) {
        // ---- C1 init: per-W-col bias (K5-prescaled), same for both m-tiles ----
        // wcol(reg r, h) = w*64 + tt*32 + 8*(r>>2) + 4*h + (r&3)
        v16f C1[2][2];
        {
            const float* bl = bhs + l * 256 + w * 64 + h * 4;
            #pragma unroll
            for (int tt = 0; tt < 2; tt++)
                #pragma unroll
                for (int rq = 0; rq < 4; rq++) {
                    v4f b = *(const v4f*)(bl + tt * 32 + rq * 8);
                    #pragma unroll
                    for (int j = 0; j < 4; j++) {
                        C1[0][tt][rq * 4 + j] = b[j];
                        C1[1][tt][rq * 4 + j] = b[j];
                    }
                }
        }
        v8h gb0 = *(const v8h*)(gf + ((l * 8 + w * 2 + 0) * 64 + lane) * 8);
        v8h gb1 = *(const v8h*)(gf + ((l * 8 + w * 2 + 1) * 64 + lane) * 8);

        // ---- GEMM1 (swapped): wh-frag = A, x-frag = B; depth-2 B-ring ----
        // Distance-1 covers L2-hit (~200cy) < kb-step wall (~512cy @4 w/SIMD);
        // ring-of-2 saves 16 regs vs R12's ring-of-4 -> fits 128 unified cap.
        {
            const short* bp = wh + l * 65536 + (2 * w) * 512 + lane * 8;
            v8h rb0[2], rb1[2];
            rb0[0] = *(const v8h*)(bp);
            rb1[0] = *(const v8h*)(bp + 512);
            #pragma unroll
            for (int kb = 0; kb < 16; kb++) {
                if (kb + 1 < 16) {
                    rb0[(kb + 1) & 1] = *(const v8h*)(bp + (kb + 1) * 4096);
                    rb1[(kb + 1) & 1] = *(const v8h*)(bp + (kb + 1) * 4096 + 512);
                }
                v8h a0 = *(const v8h*)&s_x[a1off0 + kb * 16];
                v8h a1 = *(const v8h*)&s_x[a1off1 + kb * 16];
                v8h bc0 = rb0[kb & 1], bc1 = rb1[kb & 1];
                C1[0][0] = MFMA32H(bc0, a0, C1[0][0]);
                C1[0][1] = MFMA32H(bc1, a0, C1[0][1]);
                C1[1][0] = MFMA32H(bc0, a1, C1[1][0]);
                C1[1][1] = MFMA32H(bc1, a1, C1[1][1]);
            }
        }
        __syncthreads();   // all waves done reading x_l

        // ---- epilogue: x = sin(C1) + sin(G); lane = fixed x-row, reg quads =
        //      4 consecutive W-cols -> packed b64 stores ----
        #pragma unroll
        for (int m = 0; m < 2; m++) {
            v8h ga = *(const v8h*)&s_g[(m * 32 + m32) * GSTRIDE + l * 8];
            const int rowb = (m * 32 + m32) * XSTRIDE;
            #pragma unroll
            for (int tt = 0; tt < 2; tt++) {
                v16f Z = {};
                v16f G = MFMA32H((tt ? gb1 : gb0), ga, Z);
                const int cb = rowb + w * 64 + tt * 32 + h * 4;
                #pragma unroll
                for (int rq = 0; rq < 4; rq++) {
                    v4h pv;
                    #pragma unroll
                    for (int j = 0; j < 4; j++)
                        pv[j] = (_Float16)(sin_rev(C1[m][tt][rq * 4 + j])
                                         + sin_rev(G[rq * 4 + j]));
                    *(v4h*)(s_x + cb + rq * 8) = pv;    // 8B aligned
                }
            }
        }
        __syncthreads();   // new x visible

        // ---- head GEMM, 32x32x16: wave = quadrant (mq,tq); x = A (reuses
        //      a1off bases), whh 32-col tiles = B; 16 b128 A-reads ----
        {
            const float b2 = bhhs[l * 64 + tq * 32 + m32];
            v16f C2;
            #pragma unroll
            for (int r = 0; r < 16; r++) C2[r] = b2;
            const short* bp2 = whh + l * 16384 + tq * 512 + lane * 8;
            v8h bc[16];
            #pragma unroll
            for (int kb = 0; kb < 16; kb++)
                bc[kb] = *(const v8h*)(bp2 + kb * 1024);
            const int aoff = mq ? a1off1 : a1off0;
            #pragma unroll
            for (int kb = 0; kb < 16; kb++) {
                v8h a = *(const v8h*)&s_x[aoff + kb * 16];
                C2 = MFMA32H(a, bc[kb], C2);
            }
            #pragma unroll
            for (int r = 0; r < 16; r++) cout[r] += sin_rev(C2[r]);
        }
        // no barrier: next GEMM1 reads same x; overwrites after its own barrier
    }

    // ---- store x_out: row = mq*32 + regpat, col = tq*32 + m32 (32-wide) ----
    #pragma unroll
    for (int r = 0; r < 16; r++) {
        const int orow = row0 + mq * 32 + (r & 3) + 8 * (r >> 2) + 4 * h;
        out[orow * 64 + tq * 32 + m32] = cout[r];
    }
}

extern "C" void kernel_launch(void* const* d_in, const int* in_sizes, int n_in,
                              void* d_out, int out_size, void* d_ws, size_t ws_size,
                              hipStream_t stream) {
    const float* pos   = (const float*)d_in[0];
    const float* gfeat = (const float*)d_in[1];
    const float* ffnA  = (const float*)d_in[2];
    const float* W0    = (const float*)d_in[3];
    const float* b0    = (const float*)d_in[4];
    const float* Wh    = (const float*)d_in[5];
    const float* bh    = (const float*)d_in[6];
    const float* Whh   = (const float*)d_in[7];
    const float* bhh   = (const float*)d_in[8];
    float* out = (float*)d_out;
    const int N = in_sizes[0] / 3;

    // ws: wh 327680 | whh 81920 | gf 20480 shorts, then bhs 1280 | bhhs 320 f32
    short* wh  = (short*)d_ws;
    short* whh = wh + 327680;
    short* gf  = whh + 81920;
    float* bhs  = (float*)(gf + 20480);     // byte offset 860160, 16B aligned
    float* bhhs = bhs + 1280;

    ffb_pack<<<217, 256, 0, stream>>>(Wh, Whh, ffnA, bh, bhh,
                                      wh, whh, gf, bhs, bhhs);
    ffb_main<<<N / TM, 256, 0, stream>>>(pos, gfeat, W0, b0, bhs, bhhs,
                                         wh, whh, gf, out);
}

// Round 3
// 240.639 us; speedup vs baseline: 1.0139x; 1.0139x over previous
//
#include <hip/hip_runtime.h>

// FFB encoder fused kernel, MI355X (gfx950). Round 14.
//  R13 post-mortem: (256,4) raised occupancy 28->37% but SPILLED again
//  (WRITE 32.8->65.5 MB, dur 160->171). VGPR_Count=64 revealed the unified
//  128-reg budget splits 64 VGPR + 64 AGPR (C1 fills the AGPR half). The
//  spiller is the HEAD phase: bc[16] full preload = 64 VGPRs on its own.
//  GEMM1 (56 VGPR) and epilogue (52 VGPR) phases fit.
//  R14: keep (256,4); head B-stream preload -> ring-4/distance-3 (16 VGPRs).
//   Head phase now ~42 VGPR + C2 in dead-C1's AGPRs. Cover: whh L2-resident
//   (~200cy); kb-step wall at 4 waves/SIMD ~128cy; distance-3 ~384cy. OK.
//   Spill tripwire: WRITE_SIZE must return to ~32.8 MB, FETCH to ~14.5 MB.
//   If not, (256,4) is dead -> revert to (256,3) next round.
//  Kept from R12/R13: GEMM1/grid operand swap (packed b64 epilogue stores),
//  32x32x16 head GEMM, GEMM1 ring-2/distance-1, K5-prescaled biases,
//  stride-264 LDS, 2 barriers/layer, hi-only grid branch.

#define TM 64
#define XSTRIDE 264
#define GSTRIDE 48
#define K5 0.79577471545947667f         // 5/(2*pi)

typedef __attribute__((ext_vector_type(8))) _Float16 v8h;
typedef __attribute__((ext_vector_type(4))) _Float16 v4h;
typedef __attribute__((ext_vector_type(4))) float v4f;
typedef __attribute__((ext_vector_type(16))) float v16f;

#define MFMA32H(a, b, c) __builtin_amdgcn_mfma_f32_32x32x16_f16(a, b, c, 0, 0, 0)

__device__ __forceinline__ float sin_rev(float u) {
#if __has_builtin(__builtin_amdgcn_fractf)
    return __builtin_amdgcn_sinf(__builtin_amdgcn_fractf(u));
#else
    return __builtin_amdgcn_sinf(u - floorf(u));
#endif
}

__device__ __forceinline__ short f16s(float x) {      // RNE f32->f16
    _Float16 hh = (_Float16)x;
    return __builtin_bit_cast(short, hh);
}

// ---------------- weight packing ----------------
// wh   f16: [l][kb16][nt8][lane64][8]  (327680 shorts), scaled by K5
// whh  f16: [l][kb16][nt2][lane64][8]  (81920 shorts),  scaled by K5  (32-col tiles)
// gf   f16: [l][nt8][lane64][8]        (20480 shorts),  ffnA*2^(l-1)
// bhs  f32: [l][256]  = bh*K5          (1280 floats)
// bhhs f32: [l][64]   = bhh*K5         (320 floats)
__global__ __launch_bounds__(256) void ffb_pack(
    const float* __restrict__ Wh, const float* __restrict__ Whh,
    const float* __restrict__ ffnA,
    const float* __restrict__ bh, const float* __restrict__ bhh,
    short* __restrict__ wh, short* __restrict__ whh, short* __restrict__ gf,
    float* __restrict__ bhs, float* __restrict__ bhhs)
{
    int t = blockIdx.x * 256 + threadIdx.x;
    if (t < 40960) {                       // (l, kb, nt, lane)
        int lane = t & 63, nt = (t >> 6) & 7, kb = (t >> 9) & 15, l = t >> 13;
        int n = nt * 32 + (lane & 31);
        int k0 = kb * 16 + (lane >> 5) * 8;
        short hs[8];
        #pragma unroll
        for (int jj = 0; jj < 8; jj++)
            hs[jj] = f16s(Wh[(l * 256 + k0 + jj) * 256 + n] * K5);
        *(v8h*)(wh + t * 8) = *(v8h*)hs;
    } else if (t < 51200) {
        int t2 = t - 40960;                // (l, kb16, nt2, lane)
        int lane = t2 & 63, nt = (t2 >> 6) & 1, kb = (t2 >> 7) & 15, l = t2 >> 11;
        int n = nt * 32 + (lane & 31);
        int k0 = kb * 16 + (lane >> 5) * 8;
        short hs[8];
        #pragma unroll
        for (int jj = 0; jj < 8; jj++)
            hs[jj] = f16s(Whh[(l * 256 + k0 + jj) * 64 + n] * K5);
        *(v8h*)(whh + t2 * 8) = *(v8h*)hs;
    } else if (t < 53760) {
        int t3 = t - 51200;                // (l, nt, lane)
        int lane = t3 & 63, nt = (t3 >> 6) & 7, l = t3 >> 9;
        int n = nt * 32 + (lane & 31);
        const float sc = 0.5f * (float)(1 << l);       // 2^(l-1), exact
        short hs[8];
        #pragma unroll
        for (int jj = 0; jj < 8; jj++)
            hs[jj] = f16s(ffnA[(l * 8 + jj) * 256 + n] * sc);
        *(v8h*)(gf + t3 * 8) = *(v8h*)hs;
    } else if (t < 55040) {
        int t4 = t - 53760;
        bhs[t4] = bh[t4] * K5;
    } else if (t < 55360) {
        int t5 = t - 55040;
        bhhs[t5] = bhh[t5] * K5;
    }
}

// ---------------- main fused kernel ----------------
__global__ __launch_bounds__(256, 4) void ffb_main(
    const float* __restrict__ pos, const float* __restrict__ gfeat,
    const float* __restrict__ W0, const float* __restrict__ b0,
    const float* __restrict__ bhs, const float* __restrict__ bhhs,
    const short* __restrict__ wh, const short* __restrict__ whh,
    const short* __restrict__ gf,
    float* __restrict__ out)
{
    __shared__ __align__(16) short s_x[TM * XSTRIDE];   // f16  (33792 B)
    __shared__ __align__(16) short s_g[TM * GSTRIDE];   // f16  (6144 B)
    __shared__ float s_pos[TM * 3];                     //      (768 B)

    const int tid = threadIdx.x;
    const int row0 = blockIdx.x * TM;
    const int lane = tid & 63;
    const int w = tid >> 6;
    const int m32 = lane & 31;
    const int h = lane >> 5;
    const int mq = w >> 1;                 // head-GEMM quadrant row-tile
    const int tq = w & 1;                  // head-GEMM quadrant col-tile

    if (tid < TM * 3) s_pos[tid] = pos[row0 * 3 + tid];
    for (int k2 = tid; k2 < TM * 40; k2 += 256) {
        int r = k2 / 40, f = k2 % 40;
        s_g[r * GSTRIDE + f] = f16s(gfeat[row0 * 40 + k2]);
    }
    __syncthreads();

    // layer 0: x = sin(5*(pos@W0 + b0))
    {
        const int c = tid;
        const float w00 = W0[c], w01 = W0[256 + c], w02 = W0[512 + c], bc = b0[c];
        #pragma unroll 4
        for (int r = 0; r < TM; r++) {
            float d = s_pos[r * 3 + 0] * w00 + s_pos[r * 3 + 1] * w01
                    + s_pos[r * 3 + 2] * w02 + bc;
            s_x[r * XSTRIDE + c] = f16s(sin_rev(d * K5));
        }
    }
    __syncthreads();

    float cout[16];
    #pragma unroll
    for (int r = 0; r < 16; r++) cout[r] = 0.f;

    const int a1off0 = m32 * XSTRIDE + h * 8;            // x-row tile 0, + kb*16
    const int a1off1 = (32 + m32) * XSTRIDE + h * 8;     // x-row tile 1

    for (int l = 0; l < 5; l++) {
        // ---- C1 init: per-W-col bias (K5-prescaled), same for both m-tiles ----
        // wcol(reg r, h) = w*64 + tt*32 + 8*(r>>2) + 4*h + (r&3)
        v16f C1[2][2];
        {
            const float* bl = bhs + l * 256 + w * 64 + h * 4;
            #pragma unroll
            for (int tt = 0; tt < 2; tt++)
                #pragma unroll
                for (int rq = 0; rq < 4; rq++) {
                    v4f b = *(const v4f*)(bl + tt * 32 + rq * 8);
                    #pragma unroll
                    for (int j = 0; j < 4; j++) {
                        C1[0][tt][rq * 4 + j] = b[j];
                        C1[1][tt][rq * 4 + j] = b[j];
                    }
                }
        }
        v8h gb0 = *(const v8h*)(gf + ((l * 8 + w * 2 + 0) * 64 + lane) * 8);
        v8h gb1 = *(const v8h*)(gf + ((l * 8 + w * 2 + 1) * 64 + lane) * 8);

        // ---- GEMM1 (swapped): wh-frag = A, x-frag = B; depth-2 B-ring ----
        {
            const short* bp = wh + l * 65536 + (2 * w) * 512 + lane * 8;
            v8h rb0[2], rb1[2];
            rb0[0] = *(const v8h*)(bp);
            rb1[0] = *(const v8h*)(bp + 512);
            #pragma unroll
            for (int kb = 0; kb < 16; kb++) {
                if (kb + 1 < 16) {
                    rb0[(kb + 1) & 1] = *(const v8h*)(bp + (kb + 1) * 4096);
                    rb1[(kb + 1) & 1] = *(const v8h*)(bp + (kb + 1) * 4096 + 512);
                }
                v8h a0 = *(const v8h*)&s_x[a1off0 + kb * 16];
                v8h a1 = *(const v8h*)&s_x[a1off1 + kb * 16];
                v8h bc0 = rb0[kb & 1], bc1 = rb1[kb & 1];
                C1[0][0] = MFMA32H(bc0, a0, C1[0][0]);
                C1[0][1] = MFMA32H(bc1, a0, C1[0][1]);
                C1[1][0] = MFMA32H(bc0, a1, C1[1][0]);
                C1[1][1] = MFMA32H(bc1, a1, C1[1][1]);
            }
        }
        __syncthreads();   // all waves done reading x_l

        // ---- epilogue: x = sin(C1) + sin(G); lane = fixed x-row, reg quads =
        //      4 consecutive W-cols -> packed b64 stores ----
        #pragma unroll
        for (int m = 0; m < 2; m++) {
            v8h ga = *(const v8h*)&s_g[(m * 32 + m32) * GSTRIDE + l * 8];
            const int rowb = (m * 32 + m32) * XSTRIDE;
            #pragma unroll
            for (int tt = 0; tt < 2; tt++) {
                v16f Z = {};
                v16f G = MFMA32H((tt ? gb1 : gb0), ga, Z);
                const int cb = rowb + w * 64 + tt * 32 + h * 4;
                #pragma unroll
                for (int rq = 0; rq < 4; rq++) {
                    v4h pv;
                    #pragma unroll
                    for (int j = 0; j < 4; j++)
                        pv[j] = (_Float16)(sin_rev(C1[m][tt][rq * 4 + j])
                                         + sin_rev(G[rq * 4 + j]));
                    *(v4h*)(s_x + cb + rq * 8) = pv;    // 8B aligned
                }
            }
        }
        __syncthreads();   // new x visible

        // ---- head GEMM, 32x32x16: wave = quadrant (mq,tq); x = A (reuses
        //      a1off bases), whh 32-col tiles = B.
        //      Ring-4/distance-3 B prefetch (16 VGPRs) -- NOT bc[16] (64 VGPRs,
        //      the R13 spiller). ----
        {
            const float b2 = bhhs[l * 64 + tq * 32 + m32];
            v16f C2;
            #pragma unroll
            for (int r = 0; r < 16; r++) C2[r] = b2;
            const short* bp2 = whh + l * 16384 + tq * 512 + lane * 8;
            v8h bc[4];
            #pragma unroll
            for (int p = 0; p < 3; p++)
                bc[p] = *(const v8h*)(bp2 + p * 1024);
            const int aoff = mq ? a1off1 : a1off0;
            #pragma unroll
            for (int kb = 0; kb < 16; kb++) {
                if (kb + 3 < 16)
                    bc[(kb + 3) & 3] = *(const v8h*)(bp2 + (kb + 3) * 1024);
                v8h a = *(const v8h*)&s_x[aoff + kb * 16];
                C2 = MFMA32H(a, bc[kb & 3], C2);
            }
            #pragma unroll
            for (int r = 0; r < 16; r++) cout[r] += sin_rev(C2[r]);
        }
        // no barrier: next GEMM1 reads same x; overwrites after its own barrier
    }

    // ---- store x_out: row = mq*32 + regpat, col = tq*32 + m32 (32-wide) ----
    #pragma unroll
    for (int r = 0; r < 16; r++) {
        const int orow = row0 + mq * 32 + (r & 3) + 8 * (r >> 2) + 4 * h;
        out[orow * 64 + tq * 32 + m32] = cout[r];
    }
}

extern "C" void kernel_launch(void* const* d_in, const int* in_sizes, int n_in,
                              void* d_out, int out_size, void* d_ws, size_t ws_size,
                              hipStream_t stream) {
    const float* pos   = (const float*)d_in[0];
    const float* gfeat = (const float*)d_in[1];
    const float* ffnA  = (const float*)d_in[2];
    const float* W0    = (const float*)d_in[3];
    const float* b0    = (const float*)d_in[4];
    const float* Wh    = (const float*)d_in[5];
    const float* bh    = (const float*)d_in[6];
    const float* Whh   = (const float*)d_in[7];
    const float* bhh   = (const float*)d_in[8];
    float* out = (float*)d_out;
    const int N = in_sizes[0] / 3;

    // ws: wh 327680 | whh 81920 | gf 20480 shorts, then bhs 1280 | bhhs 320 f32
    short* wh  = (short*)d_ws;
    short* whh = wh + 327680;
    short* gf  = whh + 81920;
    float* bhs  = (float*)(gf + 20480);     // byte offset 860160, 16B aligned
    float* bhhs = bhs + 1280;

    ffb_pack<<<217, 256, 0, stream>>>(Wh, Whh, ffnA, bh, bhh,
                                      wh, whh, gf, bhs, bhhs);
    ffb_main<<<N / TM, 256, 0, stream>>>(pos, gfeat, W0, b0, bhs, bhhs,
                                         wh, whh, gf, out);
}

// Round 4
// 235.898 us; speedup vs baseline: 1.0343x; 1.0201x over previous
//
#include <hip/hip_runtime.h>

// FFB encoder fused kernel, MI355X (gfx950). Round 15.
//  R14 post-mortem: spill traffic IDENTICAL to R13 (WRITE 65.3, FETCH 24.4 MB)
//  despite head preload 64->16 regs => head was never the spiller (its
//  operands can live in dead-C1 AGPRs; gfx950 MFMA A/B can be AGPR). The
//  spilled 16-reg live range is in the phases R13/R14 share: GEMM1/epilogue.
//  Prime suspect: gb0/gb1 (8 regs) hoisted before GEMM1 since R12, overlapping
//  the 16-reg B-ring + cout across the longest span of the kernel.
//  R15 demand reduction, keep (256,4):
//   - gb0/gb1 loads MOVED to their only use site (epilogue start). GEMM1
//     live set: ring-2(16)+a(8)+cout(16)+addr(~8) = 48 < 64.
//   - head B-ring 4 -> 2 (8 regs): head ~34 VGPR + C2/bc in dead-C1 AGPRs.
//   - epilogue: G(16)+ga(4)+gb(8)+cout(16)+temps ~ 52 < 64.
//  Spill tripwire: WRITE_SIZE ~32.8 MB / FETCH ~15 MB, else (256,4) is
//  structurally dead -> revert to (256,3) next round.
//  Kept: GEMM1/grid operand swap, packed b64 epilogue stores, 32x32x16 head,
//  GEMM1 ring-2/dist-1, K5-prescaled biases, stride-264 LDS, 2 barriers/layer.

#define TM 64
#define XSTRIDE 264
#define GSTRIDE 48
#define K5 0.79577471545947667f         // 5/(2*pi)

typedef __attribute__((ext_vector_type(8))) _Float16 v8h;
typedef __attribute__((ext_vector_type(4))) _Float16 v4h;
typedef __attribute__((ext_vector_type(4))) float v4f;
typedef __attribute__((ext_vector_type(16))) float v16f;

#define MFMA32H(a, b, c) __builtin_amdgcn_mfma_f32_32x32x16_f16(a, b, c, 0, 0, 0)

__device__ __forceinline__ float sin_rev(float u) {
#if __has_builtin(__builtin_amdgcn_fractf)
    return __builtin_amdgcn_sinf(__builtin_amdgcn_fractf(u));
#else
    return __builtin_amdgcn_sinf(u - floorf(u));
#endif
}

__device__ __forceinline__ short f16s(float x) {      // RNE f32->f16
    _Float16 hh = (_Float16)x;
    return __builtin_bit_cast(short, hh);
}

// ---------------- weight packing ----------------
// wh   f16: [l][kb16][nt8][lane64][8]  (327680 shorts), scaled by K5
// whh  f16: [l][kb16][nt2][lane64][8]  (81920 shorts),  scaled by K5  (32-col tiles)
// gf   f16: [l][nt8][lane64][8]        (20480 shorts),  ffnA*2^(l-1)
// bhs  f32: [l][256]  = bh*K5          (1280 floats)
// bhhs f32: [l][64]   = bhh*K5         (320 floats)
__global__ __launch_bounds__(256) void ffb_pack(
    const float* __restrict__ Wh, const float* __restrict__ Whh,
    const float* __restrict__ ffnA,
    const float* __restrict__ bh, const float* __restrict__ bhh,
    short* __restrict__ wh, short* __restrict__ whh, short* __restrict__ gf,
    float* __restrict__ bhs, float* __restrict__ bhhs)
{
    int t = blockIdx.x * 256 + threadIdx.x;
    if (t < 40960) {                       // (l, kb, nt, lane)
        int lane = t & 63, nt = (t >> 6) & 7, kb = (t >> 9) & 15, l = t >> 13;
        int n = nt * 32 + (lane & 31);
        int k0 = kb * 16 + (lane >> 5) * 8;
        short hs[8];
        #pragma unroll
        for (int jj = 0; jj < 8; jj++)
            hs[jj] = f16s(Wh[(l * 256 + k0 + jj) * 256 + n] * K5);
        *(v8h*)(wh + t * 8) = *(v8h*)hs;
    } else if (t < 51200) {
        int t2 = t - 40960;                // (l, kb16, nt2, lane)
        int lane = t2 & 63, nt = (t2 >> 6) & 1, kb = (t2 >> 7) & 15, l = t2 >> 11;
        int n = nt * 32 + (lane & 31);
        int k0 = kb * 16 + (lane >> 5) * 8;
        short hs[8];
        #pragma unroll
        for (int jj = 0; jj < 8; jj++)
            hs[jj] = f16s(Whh[(l * 256 + k0 + jj) * 64 + n] * K5);
        *(v8h*)(whh + t2 * 8) = *(v8h*)hs;
    } else if (t < 53760) {
        int t3 = t - 51200;                // (l, nt, lane)
        int lane = t3 & 63, nt = (t3 >> 6) & 7, l = t3 >> 9;
        int n = nt * 32 + (lane & 31);
        const float sc = 0.5f * (float)(1 << l);       // 2^(l-1), exact
        short hs[8];
        #pragma unroll
        for (int jj = 0; jj < 8; jj++)
            hs[jj] = f16s(ffnA[(l * 8 + jj) * 256 + n] * sc);
        *(v8h*)(gf + t3 * 8) = *(v8h*)hs;
    } else if (t < 55040) {
        int t4 = t - 53760;
        bhs[t4] = bh[t4] * K5;
    } else if (t < 55360) {
        int t5 = t - 55040;
        bhhs[t5] = bhh[t5] * K5;
    }
}

// ---------------- main fused kernel ----------------
__global__ __launch_bounds__(256, 4) void ffb_main(
    const float* __restrict__ pos, const float* __restrict__ gfeat,
    const float* __restrict__ W0, const float* __restrict__ b0,
    const float* __restrict__ bhs, const float* __restrict__ bhhs,
    const short* __restrict__ wh, const short* __restrict__ whh,
    const short* __restrict__ gf,
    float* __restrict__ out)
{
    __shared__ __align__(16) short s_x[TM * XSTRIDE];   // f16  (33792 B)
    __shared__ __align__(16) short s_g[TM * GSTRIDE];   // f16  (6144 B)
    __shared__ float s_pos[TM * 3];                     //      (768 B)

    const int tid = threadIdx.x;
    const int row0 = blockIdx.x * TM;
    const int lane = tid & 63;
    const int w = tid >> 6;
    const int m32 = lane & 31;
    const int h = lane >> 5;
    const int mq = w >> 1;                 // head-GEMM quadrant row-tile
    const int tq = w & 1;                  // head-GEMM quadrant col-tile

    if (tid < TM * 3) s_pos[tid] = pos[row0 * 3 + tid];
    for (int k2 = tid; k2 < TM * 40; k2 += 256) {
        int r = k2 / 40, f = k2 % 40;
        s_g[r * GSTRIDE + f] = f16s(gfeat[row0 * 40 + k2]);
    }
    __syncthreads();

    // layer 0: x = sin(5*(pos@W0 + b0))
    {
        const int c = tid;
        const float w00 = W0[c], w01 = W0[256 + c], w02 = W0[512 + c], bc = b0[c];
        #pragma unroll 4
        for (int r = 0; r < TM; r++) {
            float d = s_pos[r * 3 + 0] * w00 + s_pos[r * 3 + 1] * w01
                    + s_pos[r * 3 + 2] * w02 + bc;
            s_x[r * XSTRIDE + c] = f16s(sin_rev(d * K5));
        }
    }
    __syncthreads();

    float cout[16];
    #pragma unroll
    for (int r = 0; r < 16; r++) cout[r] = 0.f;

    const int a1off0 = m32 * XSTRIDE + h * 8;            // x-row tile 0, + kb*16
    const int a1off1 = (32 + m32) * XSTRIDE + h * 8;     // x-row tile 1

    for (int l = 0; l < 5; l++) {
        // ---- C1 init: per-W-col bias (K5-prescaled), same for both m-tiles ----
        // wcol(reg r, h) = w*64 + tt*32 + 8*(r>>2) + 4*h + (r&3)
        v16f C1[2][2];
        {
            const float* bl = bhs + l * 256 + w * 64 + h * 4;
            #pragma unroll
            for (int tt = 0; tt < 2; tt++)
                #pragma unroll
                for (int rq = 0; rq < 4; rq++) {
                    v4f b = *(const v4f*)(bl + tt * 32 + rq * 8);
                    #pragma unroll
                    for (int j = 0; j < 4; j++) {
                        C1[0][tt][rq * 4 + j] = b[j];
                        C1[1][tt][rq * 4 + j] = b[j];
                    }
                }
        }

        // ---- GEMM1 (swapped): wh-frag = A, x-frag = B; depth-2 B-ring ----
        // NOTE: gb0/gb1 intentionally NOT loaded here (R15): their 8-reg live
        // range overlapping the 16-reg ring was the prime spill suspect.
        {
            const short* bp = wh + l * 65536 + (2 * w) * 512 + lane * 8;
            v8h rb0[2], rb1[2];
            rb0[0] = *(const v8h*)(bp);
            rb1[0] = *(const v8h*)(bp + 512);
            #pragma unroll
            for (int kb = 0; kb < 16; kb++) {
                if (kb + 1 < 16) {
                    rb0[(kb + 1) & 1] = *(const v8h*)(bp + (kb + 1) * 4096);
                    rb1[(kb + 1) & 1] = *(const v8h*)(bp + (kb + 1) * 4096 + 512);
                }
                v8h a0 = *(const v8h*)&s_x[a1off0 + kb * 16];
                v8h a1 = *(const v8h*)&s_x[a1off1 + kb * 16];
                v8h bc0 = rb0[kb & 1], bc1 = rb1[kb & 1];
                C1[0][0] = MFMA32H(bc0, a0, C1[0][0]);
                C1[0][1] = MFMA32H(bc1, a0, C1[0][1]);
                C1[1][0] = MFMA32H(bc0, a1, C1[1][0]);
                C1[1][1] = MFMA32H(bc1, a1, C1[1][1]);
            }
        }
        __syncthreads();   // all waves done reading x_l

        // ---- epilogue: x = sin(C1) + sin(G); gb loaded AT USE (L2-resident,
        //      2 loads/layer); lane = fixed x-row, reg quads = 4 consecutive
        //      W-cols -> packed b64 stores ----
        {
            v8h gb0 = *(const v8h*)(gf + ((l * 8 + w * 2 + 0) * 64 + lane) * 8);
            v8h gb1 = *(const v8h*)(gf + ((l * 8 + w * 2 + 1) * 64 + lane) * 8);
            #pragma unroll
            for (int m = 0; m < 2; m++) {
                v8h ga = *(const v8h*)&s_g[(m * 32 + m32) * GSTRIDE + l * 8];
                const int rowb = (m * 32 + m32) * XSTRIDE;
                #pragma unroll
                for (int tt = 0; tt < 2; tt++) {
                    v16f Z = {};
                    v16f G = MFMA32H((tt ? gb1 : gb0), ga, Z);
                    const int cb = rowb + w * 64 + tt * 32 + h * 4;
                    #pragma unroll
                    for (int rq = 0; rq < 4; rq++) {
                        v4h pv;
                        #pragma unroll
                        for (int j = 0; j < 4; j++)
                            pv[j] = (_Float16)(sin_rev(C1[m][tt][rq * 4 + j])
                                             + sin_rev(G[rq * 4 + j]));
                        *(v4h*)(s_x + cb + rq * 8) = pv;    // 8B aligned
                    }
                }
            }
        }
        __syncthreads();   // new x visible

        // ---- head GEMM, 32x32x16: wave = quadrant (mq,tq); x = A (reuses
        //      a1off bases), whh 32-col tiles = B; ring-2/dist-1 (8 VGPRs) ----
        {
            const float b2 = bhhs[l * 64 + tq * 32 + m32];
            v16f C2;
            #pragma unroll
            for (int r = 0; r < 16; r++) C2[r] = b2;
            const short* bp2 = whh + l * 16384 + tq * 512 + lane * 8;
            v8h bc[2];
            bc[0] = *(const v8h*)(bp2);
            const int aoff = mq ? a1off1 : a1off0;
            #pragma unroll
            for (int kb = 0; kb < 16; kb++) {
                if (kb + 1 < 16)
                    bc[(kb + 1) & 1] = *(const v8h*)(bp2 + (kb + 1) * 1024);
                v8h a = *(const v8h*)&s_x[aoff + kb * 16];
                C2 = MFMA32H(a, bc[kb & 1], C2);
            }
            #pragma unroll
            for (int r = 0; r < 16; r++) cout[r] += sin_rev(C2[r]);
        }
        // no barrier: next GEMM1 reads same x; overwrites after its own barrier
    }

    // ---- store x_out: row = mq*32 + regpat, col = tq*32 + m32 (32-wide) ----
    #pragma unroll
    for (int r = 0; r < 16; r++) {
        const int orow = row0 + mq * 32 + (r & 3) + 8 * (r >> 2) + 4 * h;
        out[orow * 64 + tq * 32 + m32] = cout[r];
    }
}

extern "C" void kernel_launch(void* const* d_in, const int* in_sizes, int n_in,
                              void* d_out, int out_size, void* d_ws, size_t ws_size,
                              hipStream_t stream) {
    const float* pos   = (const float*)d_in[0];
    const float* gfeat = (const float*)d_in[1];
    const float* ffnA  = (const float*)d_in[2];
    const float* W0    = (const float*)d_in[3];
    const float* b0    = (const float*)d_in[4];
    const float* Wh    = (const float*)d_in[5];
    const float* bh    = (const float*)d_in[6];
    const float* Whh   = (const float*)d_in[7];
    const float* bhh   = (const float*)d_in[8];
    float* out = (float*)d_out;
    const int N = in_sizes[0] / 3;

    // ws: wh 327680 | whh 81920 | gf 20480 shorts, then bhs 1280 | bhhs 320 f32
    short* wh  = (short*)d_ws;
    short* whh = wh + 327680;
    short* gf  = whh + 81920;
    float* bhs  = (float*)(gf + 20480);     // byte offset 860160, 16B aligned
    float* bhhs = bhs + 1280;

    ffb_pack<<<217, 256, 0, stream>>>(Wh, Whh, ffnA, bh, bhh,
                                      wh, whh, gf, bhs, bhhs);
    ffb_main<<<N / TM, 256, 0, stream>>>(pos, gfeat, W0, b0, bhs, bhhs,
                                         wh, whh, gf, out);
}